// Round 14
// baseline (247.171 us; speedup 1.0000x reference)
//
#include <hip/hip_runtime.h>
#include <hip/hip_bf16.h>

// tRNN fused: embedding -> 6 tree levels (MFMA bf16) -> cpr -> softmax
// R14 = R13 + 2 rows per block: A-frag/bias load amortized x2, grid 4096,
//       row-1 leaves register-prefetched in the epilogue window (issued
//       before cpr, written after softmax — never live during level phases,
//       unlike R12's spiller). z in separate 512B LDS array (prefetch-safe).
// B=8192, SIDES=2, L=64, V=10000, D=128, C=128, R=7

typedef __attribute__((ext_vector_type(8))) short bf16x8;
typedef __attribute__((ext_vector_type(4))) float f32x4;

#define VOCN (10000 * 128)
#define CPSN (128 * 256)
#define CPRN (128 * 256)

__device__ __forceinline__ uint pk2(float a, float b) {
  union { __hip_bfloat162 h2; uint u; } cv;
  cv.h2 = __float22bfloat162_rn(make_float2(a, b));
  return cv.u;
}
__device__ __forceinline__ float2 up2(uint u) {
  union { uint u; __hip_bfloat162 h2; } cv; cv.u = u;
  return __bfloat1622float2(cv.h2);
}
__device__ __forceinline__ float fast_tanh(float x) {
  float e = __builtin_amdgcn_exp2f(x * 2.88539008f);   // exp(2x)
  return 1.0f - 2.0f * __builtin_amdgcn_rcpf(e + 1.0f);
}

// ---- prep: f32 -> bf16 (voc fused with bias) into d_ws ----
__global__ void prep_kernel(const float* __restrict__ voc_w, const float* __restrict__ voc_b,
                            const float* __restrict__ cps_w, const float* __restrict__ cpr_w,
                            ushort* __restrict__ ws) {
  const int i4 = (blockIdx.x * 256 + threadIdx.x) * 4;
  if (i4 >= VOCN + CPSN + CPRN) return;
  float4 v;
  if (i4 < VOCN) {
    v = *(const float4*)(voc_w + i4);
    const float4 bb = *(const float4*)(voc_b + (i4 & 127));
    v.x += bb.x; v.y += bb.y; v.z += bb.z; v.w += bb.w;
  } else if (i4 < VOCN + CPSN) {
    v = *(const float4*)(cps_w + (i4 - VOCN));
  } else {
    v = *(const float4*)(cpr_w + (i4 - VOCN - CPSN));
  }
  uint2 w; w.x = pk2(v.x, v.y); w.y = pk2(v.z, v.w);
  *(uint2*)(ws + i4) = w;
}

// LDS layout per tree (16 KB): elem k of PHYS slot s at byte
//   (k>>3)*1024 + s*16 + (k&7)*2 ; tree1 at +16384.
// Per-level logical->phys: node i -> (i&1)*H + (i>>1)  (lane-contiguous reads).
#define MFMA16(Ax, Bx, Cx) __builtin_amdgcn_mfma_f32_16x16x32_bf16(Ax, Bx, Cx, 0, 0, 0)

template<int TOFF>
__device__ __forceinline__ void tile16(const char* hb, const bf16x8 (&A)[2][8],
                                       int RL, int RR, f32x4& aA, f32x4& aB) {
  bf16x8 bl[4], br[4];
#pragma unroll
  for (int q = 0; q < 4; ++q) {
    bl[q] = *(const bf16x8*)(hb + RL + TOFF + q * 4096);
    br[q] = *(const bf16x8*)(hb + RR + TOFF + q * 4096);
  }
#pragma unroll
  for (int q = 0; q < 4; ++q) {
    aA = MFMA16(A[0][q], bl[q], aA);
    aB = MFMA16(A[1][q], bl[q], aB);
  }
#pragma unroll
  for (int q = 0; q < 4; ++q) {
    aA = MFMA16(A[0][4 + q], br[q], aA);
    aB = MFMA16(A[1][4 + q], br[q], aB);
  }
}

template<int TOFF>
__device__ __forceinline__ void wtile(char* hb, int W, const f32x4& aA, const f32x4& aB) {
  uint2 w0, w1;
  w0.x = pk2(fast_tanh(aA[0]), fast_tanh(aA[1]));
  w0.y = pk2(fast_tanh(aA[2]), fast_tanh(aA[3]));
  w1.x = pk2(fast_tanh(aB[0]), fast_tanh(aB[1]));
  w1.y = pk2(fast_tanh(aB[2]), fast_tanh(aB[3]));
  *(uint2*)(hb + W + TOFF) = w0;
  *(uint2*)(hb + W + TOFF + 2048) = w1;
}

template<int PRE>
__global__ __launch_bounds__(256, 4)
void trnn_kernel(const int* __restrict__ tokens,
                 const float* __restrict__ voc_w, const float* __restrict__ voc_b,
                 const float* __restrict__ cps_w, const float* __restrict__ cps_b,
                 const float* __restrict__ cpr_w, const float* __restrict__ cpr_b,
                 const float* __restrict__ sm_w, const float* __restrict__ sm_b,
                 const ushort* __restrict__ wsb, float* __restrict__ out) {
  __shared__ ushort h[16384];      // 32 KB: 2 trees x (16 chunks x 64 slots x 16B)
  __shared__ float z2[128];        // z scratch (prefetch-safe, outside tree slots)
  const int tid = threadIdx.x;
  const int lane = tid & 63, wv = tid >> 6;
  const int l15 = lane & 15, lh = lane >> 4;
  const int b0 = blockIdx.x * 2;
  char* hb = (char*)h;

  const ushort* voc_bf = wsb;
  const ushort* cps_bf = wsb + VOCN;
  const ushort* cpr_bf = wsb + VOCN + CPSN;

  // ---- per-lane LDS bases (R13 contiguous-slot scheme) ----
  const int lhb = lh * 1024;
  const int lb16 = l15 * 16;
  const int RLa = lhb + lb16;            // slots  0-15
  const int RLb = lhb + 256 + lb16;      // slots 16-31
  const int RRa = lhb + 512 + lb16;      // slots 32-47
  const int RRb = lhb + 768 + lb16;      // slots 48-63
  const int t3 = ((l15 >> 3) & 1) << 14;
  const int RL3 = t3 + lhb + (l15 & 7) * 16;          // slots 0-7
  const int RR3 = RL3 + 128;                          // slots 8-15
  const int t4 = ((l15 >> 2) & 1) << 14;
  const int RL4 = t4 + lhb + (l15 & 3) * 16;          // slots 0-3
  const int RR4 = RL4 + 64;                           // slots 4-7
  const int t5 = ((l15 >> 1) & 1) << 14;
  const int RL5 = t5 + lhb + (l15 & 1) * 16;          // slots 0-1
  const int RR5 = RL5 + 32;                           // slots 2-3
  const int t6 = (l15 & 1) << 14;
  const int RL6 = t6 + lhb;                           // slot 0
  const int RR6 = RL6 + 16;                           // slot 1
  const int dpart = (((wv * 32 + lh * 4) >> 3) << 10) + ((lh & 1) << 3);
  const int Wa = ((l15 & 1) * 16 + (l15 >> 1)) * 16 + dpart;
  const int Wb = Wa + 128;
  const int W2 = ((l15 & 1) * 8 + (l15 >> 1)) * 16 + dpart;
  const int W3 = t3 + (((l15 & 1) * 4 + ((l15 & 7) >> 1)) * 16) + dpart;
  const int W4 = t4 + (((l15 & 1) * 2 + ((l15 & 3) >> 1)) * 16) + dpart;
  const int W5 = t5 + ((l15 & 1) * 16) + dpart;
  const int W6 = t6 + dpart;                           // root -> slot 0

  // ---- cps weights -> A fragments; biases -> regs ----
  bf16x8 A[2][8];
  f32x4 bias[2];
#pragma unroll
  for (int mt = 0; mt < 2; ++mt) {
    const int d = wv * 32 + mt * 16 + l15;
#pragma unroll
    for (int kt = 0; kt < 8; ++kt) {
      const int k = kt * 32 + lh * 8;
      if constexpr (PRE) {
        A[mt][kt] = *(const bf16x8*)(cps_bf + d * 256 + k);
      } else {
        const float* p = cps_w + d * 256 + k;
        float4 lo = *(const float4*)p, hi = *(const float4*)(p + 4);
        union { bf16x8 v; uint4 u; } f;
        f.u.x = pk2(lo.x, lo.y); f.u.y = pk2(lo.z, lo.w);
        f.u.z = pk2(hi.x, hi.y); f.u.w = pk2(hi.z, hi.w);
        A[mt][kt] = f.v;
      }
    }
    const float4 bb = *(const float4*)(cps_b + wv * 32 + mt * 16 + lh * 4);
    bias[mt][0] = bb.x; bias[mt][1] = bb.y; bias[mt][2] = bb.z; bias[mt][3] = bb.w;
  }

  // ---- embedding row 0: 2 threads per (tree, leaf); leaf r -> slot (r&1)*32+(r>>1) ----
  const int tree_e = tid >> 7, lf_e = (tid >> 1) & 63, half_e = tid & 1;
  const int p_e = (lf_e & 1) * 32 + (lf_e >> 1);
  char* tp = hb + tree_e * 16384 + half_e * 8192 + p_e * 16;
  {
    const int tok = tokens[b0 * 128 + tree_e * 64 + lf_e];
    if constexpr (PRE) {
      const ushort* vr = voc_bf + tok * 128 + half_e * 64;
#pragma unroll
      for (int j = 0; j < 8; ++j) {
        const int c = (j + p_e) & 7;
        *(uint4*)(tp + c * 1024) = *(const uint4*)(vr + c * 8);
      }
    } else {
      const float* vw = voc_w + tok * 128 + half_e * 64;
      const float* vb = voc_b + half_e * 64;
#pragma unroll
      for (int j = 0; j < 8; ++j) {
        const int c = (j + p_e) & 7;
        float4 v0 = *(const float4*)(vw + c * 8);
        float4 v1 = *(const float4*)(vw + c * 8 + 4);
        float4 q0 = *(const float4*)(vb + c * 8);
        float4 q1 = *(const float4*)(vb + c * 8 + 4);
        uint4 w;
        w.x = pk2(v0.x + q0.x, v0.y + q0.y);
        w.y = pk2(v0.z + q0.z, v0.w + q0.w);
        w.z = pk2(v1.x + q1.x, v1.y + q1.y);
        w.w = pk2(v1.z + q1.z, v1.w + q1.w);
        *(uint4*)(tp + c * 1024) = w;
      }
    }
  }
  __syncthreads();

  for (int r = 0; r < 2; ++r) {
    // ---- Level 1: leaves -> 32 nodes/tree (4 tiles) ----
    {
      f32x4 a0 = bias[0], b0v = bias[1], a1 = bias[0], b1 = bias[1];
      f32x4 a2 = bias[0], b2 = bias[1], a3 = bias[0], b3 = bias[1];
      tile16<0>(hb, A, RLa, RRa, a0, b0v);
      tile16<0>(hb, A, RLb, RRb, a1, b1);
      tile16<16384>(hb, A, RLa, RRa, a2, b2);
      tile16<16384>(hb, A, RLb, RRb, a3, b3);
      __syncthreads();
      wtile<0>(hb, Wa, a0, b0v);
      wtile<0>(hb, Wb, a1, b1);
      wtile<16384>(hb, Wa, a2, b2);
      wtile<16384>(hb, Wb, a3, b3);
      __syncthreads();
    }
    // ---- Level 2: L1-out (slots 0-31) -> 16 nodes/tree (2 tiles) ----
    {
      f32x4 a0 = bias[0], b0v = bias[1], a1 = bias[0], b1 = bias[1];
      tile16<0>(hb, A, RLa, RLb, a0, b0v);
      tile16<16384>(hb, A, RLa, RLb, a1, b1);
      __syncthreads();
      wtile<0>(hb, W2, a0, b0v);
      wtile<16384>(hb, W2, a1, b1);
      __syncthreads();
    }
    // ---- Level 3: -> 8 nodes/tree (1 tile, trees packed) ----
    {
      f32x4 a0 = bias[0], b0v = bias[1];
      tile16<0>(hb, A, RL3, RR3, a0, b0v);
      __syncthreads();
      wtile<0>(hb, W3, a0, b0v);
      __syncthreads();
    }
    // ---- Level 4: -> 4 nodes/tree (8 valid cols) ----
    {
      f32x4 a0 = bias[0], b0v = bias[1];
      tile16<0>(hb, A, RL4, RR4, a0, b0v);
      __syncthreads();
      if (l15 < 8) wtile<0>(hb, W4, a0, b0v);
      __syncthreads();
    }
    // ---- Level 5: -> 2 nodes/tree (4 valid cols) ----
    {
      f32x4 a0 = bias[0], b0v = bias[1];
      tile16<0>(hb, A, RL5, RR5, a0, b0v);
      __syncthreads();
      if (l15 < 4) wtile<0>(hb, W5, a0, b0v);
      __syncthreads();
    }
    // ---- Level 6: -> root at slot 0 (2 valid cols) ----
    {
      f32x4 a0 = bias[0], b0v = bias[1];
      tile16<0>(hb, A, RL6, RR6, a0, b0v);
      __syncthreads();
      if (l15 < 2) wtile<0>(hb, W6, a0, b0v);
      __syncthreads();
    }

    // ---- prefetch row-1 leaves (epilogue window: accs dead, pf dies pre-L1) ----
    uint4 pf[8];
    if (PRE && r == 0) {
      const int tok1 = tokens[(b0 + 1) * 128 + tree_e * 64 + lf_e];
      const ushort* vr = voc_bf + tok1 * 128 + half_e * 64;
#pragma unroll
      for (int j = 0; j < 8; ++j) pf[j] = *(const uint4*)(vr + j * 8);
    }

    // ---- cpr: 2 threads per output c; partial carve at slots 32-47 (dead) ----
    {
      const int half = tid >> 7, c = tid & 127;
      const char* rp = hb + half * 16384;   // root, slot 0
      float acc = 0.f;
#pragma unroll 4
      for (int ch = 0; ch < 16; ++ch) {
        uint4 u = *(const uint4*)(rp + ch * 1024);
        float2 e0 = up2(u.x), e1 = up2(u.y), e2 = up2(u.z), e3 = up2(u.w);
        if constexpr (PRE) {
          uint4 wq = *(const uint4*)(cpr_bf + c * 256 + half * 128 + ch * 8);
          float2 w0 = up2(wq.x), w1 = up2(wq.y), w2 = up2(wq.z), w3 = up2(wq.w);
          acc += e0.x * w0.x + e0.y * w0.y + e1.x * w1.x + e1.y * w1.y
               + e2.x * w2.x + e2.y * w2.y + e3.x * w3.x + e3.y * w3.y;
        } else {
          const float* wr = cpr_w + c * 256 + half * 128 + ch * 8;
          float4 w0 = *(const float4*)wr, w1 = *(const float4*)(wr + 4);
          acc += e0.x * w0.x + e0.y * w0.y + e1.x * w0.z + e1.y * w0.w
               + e2.x * w1.x + e2.y * w1.y + e3.x * w1.z + e3.y * w1.w;
        }
      }
      *(float*)(hb + ((tid >> 4) << 10) + 512 + ((tid & 15) << 2)) = acc;
    }
    __syncthreads();
    if (tid < 128) {
      const float p0 = *(const float*)(hb + ((tid >> 4) << 10) + 512 + ((tid & 15) << 2));
      const int j1 = tid + 128;
      const float p1 = *(const float*)(hb + ((j1 >> 4) << 10) + 512 + ((j1 & 15) << 2));
      float z = p0 + p1 + cpr_b[tid];
      z2[tid] = z > 0.f ? z : 0.01f * z;
    }
    __syncthreads();

    // ---- softmax head (wave 0) reads z2 ----
    if (wv == 0) {
      const float za = z2[lane];
      const float zc = z2[64 + lane];
      float p[7];
#pragma unroll
      for (int j = 0; j < 7; ++j)
        p[j] = za * sm_w[j * 128 + lane] + zc * sm_w[j * 128 + 64 + lane];
#pragma unroll
      for (int j = 0; j < 7; ++j) {
        float v = p[j];
#pragma unroll
        for (int off = 32; off >= 1; off >>= 1) v += __shfl_xor(v, off, 64);
        p[j] = v + sm_b[j];
      }
      float mx = p[0];
#pragma unroll
      for (int j = 1; j < 7; ++j) mx = fmaxf(mx, p[j]);
      float e[7], s = 0.f;
#pragma unroll
      for (int j = 0; j < 7; ++j) { e[j] = __expf(p[j] - mx); s += e[j]; }
      const float inv = 1.f / s;
      if (lane == 0) {
#pragma unroll
        for (int j = 0; j < 7; ++j) out[(b0 + r) * 7 + j] = e[j] * inv;
      }
    }

    // ---- write row-1 leaves (prefetched) over dead tree slots ----
    if (r == 0) {
      if constexpr (PRE) {
#pragma unroll
        for (int j = 0; j < 8; ++j)
          *(uint4*)(tp + j * 1024) = pf[j];
      } else {
        const int tok = tokens[(b0 + 1) * 128 + tree_e * 64 + lf_e];
        const float* vw = voc_w + tok * 128 + half_e * 64;
        const float* vb = voc_b + half_e * 64;
#pragma unroll
        for (int j = 0; j < 8; ++j) {
          float4 v0 = *(const float4*)(vw + j * 8);
          float4 v1 = *(const float4*)(vw + j * 8 + 4);
          float4 q0 = *(const float4*)(vb + j * 8);
          float4 q1 = *(const float4*)(vb + j * 8 + 4);
          uint4 w;
          w.x = pk2(v0.x + q0.x, v0.y + q0.y);
          w.y = pk2(v0.z + q0.z, v0.w + q0.w);
          w.z = pk2(v1.x + q1.x, v1.y + q1.y);
          w.w = pk2(v1.z + q1.z, v1.w + q1.w);
          *(uint4*)(tp + j * 1024) = w;
        }
      }
      __syncthreads();
    }
  }
}

extern "C" void kernel_launch(void* const* d_in, const int* in_sizes, int n_in,
                              void* d_out, int out_size, void* d_ws, size_t ws_size,
                              hipStream_t stream) {
  const int*   tokens = (const int*)  d_in[0];
  const float* voc_w  = (const float*)d_in[1];
  const float* voc_b  = (const float*)d_in[2];
  const float* cps_w  = (const float*)d_in[3];
  const float* cps_b  = (const float*)d_in[4];
  const float* cpr_w  = (const float*)d_in[5];
  const float* cpr_b  = (const float*)d_in[6];
  const float* sm_w   = (const float*)d_in[7];
  const float* sm_b   = (const float*)d_in[8];
  float* out = (float*)d_out;

  const int B = in_sizes[0] / 128;                     // 8192
  const size_t need = (size_t)(VOCN + CPSN + CPRN) * sizeof(ushort);

  if (ws_size >= need) {
    ushort* ws = (ushort*)d_ws;
    const int tot4 = (VOCN + CPSN + CPRN) / 4;
    prep_kernel<<<(tot4 + 255) / 256, 256, 0, stream>>>(voc_w, voc_b, cps_w, cpr_w, ws);
    trnn_kernel<1><<<B / 2, 256, 0, stream>>>(tokens, voc_w, voc_b, cps_w, cps_b,
                                              cpr_w, cpr_b, sm_w, sm_b, ws, out);
  } else {
    trnn_kernel<0><<<B / 2, 256, 0, stream>>>(tokens, voc_w, voc_b, cps_w, cps_b,
                                              cpr_w, cpr_b, sm_w, sm_b,
                                              (const ushort*)d_ws, out);
  }
}